// Round 7
// baseline (57.363 us; speedup 1.0000x reference)
//
#include <hip/hip_runtime.h>

#define NREG   20
#define EDIM   768
#define DVOL   64
#define HVOL   512
#define WVOL   512
#define HW_    (HVOL * WVOL)
#define DHW_   (DVOL * HVOL * WVOL)
#define NPATCH 16384
#define BTOT   2
#define PROTO_N (NREG * EDIM)            // 15360
#define RF_N    (BTOT * PROTO_N)         // 30720 floats (output 0)
#define TOTAL_PATCHES (BTOT * NPATCH)    // 32768
#define CHUNK   4096                     // patches per sort chunk (8 chunks)

// workspace layout (u32 words)
#define WS_PID 0
#define WS_C0  (WS_PID + TOTAL_PATCHES)
#define WS_C1  (WS_C0  + TOTAL_PATCHES)
#define WS_C2  (WS_C1  + TOTAL_PATCHES)

// 16-byte load with only 4-byte alignment guarantee.
struct __attribute__((packed, aligned(4))) int4p { int x, y, z, w; };

// DPP add: x += dpp_move(x, CTRL) — VALU pipe, no LDS.
template<int CTRL, int RM>
__device__ __forceinline__ unsigned dppadd(unsigned x)
{
    return x + (unsigned)__builtin_amdgcn_update_dpp(0, (int)x, CTRL, RM, 0xF, true);
}

// ---------------------------------------------------------------------------
// Fused single-kernel counting sort: 8 blocks, each sorts its own 4096-patch
// chunk by spatial key (z/2 -> 32 bins, y/32 -> 16 bins = 512 buckets) into
// ws (pid + SoA coords). Chunk ranges line up with assign's XCD swizzle.
// ---------------------------------------------------------------------------
__global__ __launch_bounds__(1024) void sort_kernel(
    const float* __restrict__ coords, unsigned* __restrict__ ws)
{
    __shared__ unsigned counts[512], offs[512];
    const int t  = threadIdx.x;
    const int p0 = (int)blockIdx.x * CHUNK + t * 4;

    if (t < 512) counts[t] = 0u;
    __syncthreads();

    // 4 consecutive patches per thread: 12 contiguous floats
    float c[12];
    {
        const float4* cp = (const float4*)(coords + p0 * 3);
        const float4 a = cp[0], b = cp[1], d = cp[2];
        c[0]=a.x; c[1]=a.y; c[2]=a.z;  c[3]=a.w; c[4]=b.x; c[5]=b.y;
        c[6]=b.z; c[7]=b.w; c[8]=d.x;  c[9]=d.y; c[10]=d.z; c[11]=d.w;
    }
    unsigned key[4];
#pragma unroll
    for (int i = 0; i < 4; ++i) {
        const int zb = ((int)(c[3*i + 0] * 64.0f))  >> 1;   // 0..31
        const int yb = ((int)(c[3*i + 1] * 512.0f)) >> 5;   // 0..15
        key[i] = (unsigned)(zb * 16 + yb);
        atomicAdd(&counts[key[i]], 1u);
    }
    __syncthreads();

    if (t < 512) offs[t] = counts[t];
    __syncthreads();
#pragma unroll
    for (int off = 1; off < 512; off <<= 1) {
        const unsigned v = (t >= off && t < 512) ? offs[t - off] : 0u;
        __syncthreads();
        if (t < 512) offs[t] += v;
        __syncthreads();
    }
    if (t < 512) offs[t] -= counts[t];        // exclusive prefix
    __syncthreads();

#pragma unroll
    for (int i = 0; i < 4; ++i) {
        const unsigned rank = (unsigned)blockIdx.x * CHUNK
                            + atomicAdd(&offs[key[i]], 1u);
        ws[WS_PID + rank] = (unsigned)(p0 + i);
        ((float*)ws)[WS_C0 + rank] = c[3*i + 0];
        ((float*)ws)[WS_C1 + rank] = c[3*i + 1];
        ((float*)ws)[WS_C2 + rank] = c[3*i + 2];
    }
}

// ---------------------------------------------------------------------------
// One wave per sorted slot. 4 unconditional int4 gathers, packed 8-bit
// histogram, DPP wave reduction (zero LDS ops, no __syncthreads).
// Blocks 0..119 also copy the prototype broadcast (output 0).
// ---------------------------------------------------------------------------
__global__ __launch_bounds__(256) void assign_kernel(
    const int*      __restrict__ seg,
    const unsigned* __restrict__ ws,
    const float*    __restrict__ proto,
    float*          __restrict__ out)
{
    // fused output 0: region_features = broadcast prototypes (120 blocks)
    if (blockIdx.x < RF_N / 256) {
        const int i = blockIdx.x * 256 + threadIdx.x;
        out[i] = proto[i >= PROTO_N ? i - PROTO_N : i];
    }

    // XCD-chunked swizzle: block bid -> sorted chunk (bid & 7)
    const int bid  = (int)blockIdx.x;
    const int sbid = (bid & 7) * 1024 + (bid >> 3);

    const int lane = threadIdx.x & 63;
    const int wave = threadIdx.x >> 6;
    const int slot = sbid * 4 + wave;

    const int   patch = (int)ws[WS_PID + slot];                  // uniform
    const float c0 = ((const float*)ws)[WS_C0 + slot] * 64.0f;   // z
    const float c1 = ((const float*)ws)[WS_C1 + slot] * 512.0f;  // y
    const float c2 = ((const float*)ws)[WS_C2 + slot] * 512.0f;  // x
    const int b = patch >> 14;

    const int sz = (int)fmaxf(0.0f,   floorf(c0 - 2.0f));
    const int ez = (int)fminf(64.0f,  floorf(c0 + 2.0f));
    const int sy = (int)fmaxf(0.0f,   floorf(c1 - 8.0f));
    const int ey = (int)fminf(512.0f, floorf(c1 + 8.0f));
    const int sx = (int)fmaxf(0.0f,   floorf(c2 - 8.0f));
    const int ex = (int)fminf(512.0f, floorf(c2 + 8.0f));

    const int xl4  = lane & 3;
    const int yy   = lane >> 2;
    const int p_lo = sx + 4 * xl4;
    const int st   = min(p_lo, WVOL - 4);
    const int yi   = sy + yy;
    const unsigned vy = (yi < ey) ? 0xFFFFFFFFu : 0u;
    const int yiC  = min(yi, HVOL - 1);
    const int rowbase = b * DHW_ + yiC * WVOL + st;

    unsigned vm[4];
#pragma unroll
    for (int j = 0; j < 4; ++j) {
        const int pos = st + j;
        vm[j] = (pos >= p_lo && pos < ex) ? vy : 0u;
    }

    // --- 4 unconditional gathers, issued back-to-back ----------------------
    int4p q0, q1, q2, q3;
    {
        const int z0 = min(sz + 0, DVOL - 1) * HW_;
        const int z1 = min(sz + 1, DVOL - 1) * HW_;
        const int z2 = min(sz + 2, DVOL - 1) * HW_;
        const int z3 = min(sz + 3, DVOL - 1) * HW_;
        q0 = *(const int4p*)(seg + rowbase + z0);
        q1 = *(const int4p*)(seg + rowbase + z1);
        q2 = *(const int4p*)(seg + rowbase + z2);
        q3 = *(const int4p*)(seg + rowbase + z3);
    }

    // --- packed 8-bit histogram: cc[k] holds regions 4k..4k+3 --------------
    unsigned cc[5] = {0u, 0u, 0u, 0u, 0u};
#pragma unroll
    for (int z = 0; z < 4; ++z) {
        const unsigned zm = (sz + z < ez) ? 0xFFFFFFFFu : 0u;
        const int4p qz = (z == 0) ? q0 : (z == 1) ? q1 : (z == 2) ? q2 : q3;
        const int vals[4] = {qz.x, qz.y, qz.z, qz.w};
#pragma unroll
        for (int j = 0; j < 4; ++j) {
            const int v = vals[j] & (int)(vm[j] & zm);   // invalid -> 0
            const int t = v - 1;                         // -1 if not counted
            const unsigned inc = 1u << ((t & 3) << 3);
            const int qk = t >> 2;                       // -1 matches no k
#pragma unroll
            for (int k = 0; k < 5; ++k)
                cc[k] += (qk == k) ? inc : 0u;
        }
    }

    // --- DPP wave reduction (VALU pipe only) -------------------------------
    // stage 1: prefix-8 within 16-lane rows on packed bytes (max 128, no ovf)
#pragma unroll
    for (int k = 0; k < 5; ++k) {
        cc[k] = dppadd<0x111, 0xF>(cc[k]);   // row_shr:1
        cc[k] = dppadd<0x112, 0xF>(cc[k]);   // row_shr:2
        cc[k] = dppadd<0x114, 0xF>(cc[k]);   // row_shr:4
    }
    // unpack to 2x16-bit fields
    unsigned lo[5], hi[5];
#pragma unroll
    for (int k = 0; k < 5; ++k) {
        lo[k] = cc[k] & 0x00FF00FFu;          // regions 4k (lo16), 4k+2 (hi16)
        hi[k] = (cc[k] >> 8) & 0x00FF00FFu;   // regions 4k+1,      4k+3
    }
    // stage 2: finish rows + cross-row broadcast; lane 63 holds totals
#pragma unroll
    for (int k = 0; k < 5; ++k) {
        lo[k] = dppadd<0x118, 0xF>(lo[k]);    // row_shr:8
        hi[k] = dppadd<0x118, 0xF>(hi[k]);
        lo[k] = dppadd<0x142, 0xA>(lo[k]);    // row_bcast:15, rows 1,3
        hi[k] = dppadd<0x142, 0xA>(hi[k]);
        lo[k] = dppadd<0x143, 0xC>(lo[k]);    // row_bcast:31, rows 2,3
        hi[k] = dppadd<0x143, 0xC>(hi[k]);
    }

    // totals to scalar regs (wave-uniform)
    unsigned cl[5], ch[5];
#pragma unroll
    for (int k = 0; k < 5; ++k) {
        cl[k] = (unsigned)__builtin_amdgcn_readlane((int)lo[k], 63);
        ch[k] = (unsigned)__builtin_amdgcn_readlane((int)hi[k], 63);
    }

    unsigned S = 0u;
#pragma unroll
    for (int k = 0; k < 5; ++k) S += cl[k] + ch[k];
    const unsigned tot = (S & 0xFFFFu) + (S >> 16);   // total <= 1024, no carry

    // per-lane region count via static select chain
    unsigned cnt = 0u;
#pragma unroll
    for (int k = 0; k < 5; ++k) {
        cnt = (lane == 4*k + 0) ? (cl[k] & 0xFFFFu) : cnt;
        cnt = (lane == 4*k + 1) ? (ch[k] & 0xFFFFu) : cnt;
        cnt = (lane == 4*k + 2) ? (cl[k] >> 16)     : cnt;
        cnt = (lane == 4*k + 3) ? (ch[k] >> 16)     : cnt;
    }

    if (lane < NREG) {
        const float nz = (float)max(ez - sz, 0);
        const float ny = (float)max(ey - sy, 0);
        const float nx = (float)max(ex - sx, 0);
        const float denom = fmaxf(nz * ny * nx, 1.0f);
        const float s = (float)tot / denom + (float)NREG * 1e-6f;
        const float a = (float)cnt / denom + 1e-6f;
        out[RF_N + patch * NREG + lane] = a / s;
    }
}

// ---------------------------------------------------------------------------
extern "C" void kernel_launch(void* const* d_in, const int* in_sizes, int n_in,
                              void* d_out, int out_size, void* d_ws, size_t ws_size,
                              hipStream_t stream)
{
    const int*   seg    = (const int*)d_in[0];
    const float* coords = (const float*)d_in[1];
    const float* proto  = (const float*)d_in[2];
    float*       out    = (float*)d_out;
    unsigned*    ws     = (unsigned*)d_ws;

    hipLaunchKernelGGL(sort_kernel, dim3(TOTAL_PATCHES / CHUNK), dim3(1024),
                       0, stream, coords, ws);
    hipLaunchKernelGGL(assign_kernel, dim3(TOTAL_PATCHES / 4), dim3(256),
                       0, stream, seg, ws, proto, out);
}